// Round 3
// baseline (333.765 us; speedup 1.0000x reference)
//
#include <hip/hip_runtime.h>
#include <hip/hip_bf16.h>

typedef float f4vec  __attribute__((ext_vector_type(4)));
typedef float f16vec __attribute__((ext_vector_type(16)));
typedef short s8vec  __attribute__((ext_vector_type(8)));

#define B_DIM 64
#define N_DIM 64
#define D_DIM 9216
#define SPLIT 8
#define CHUNK 1152          // D_DIM / SPLIT
#define NSTEP (CHUNK / 64)  // 18

// ws layout (bytes):
//   Spart    @ 0        : 64*8*4096*4 = 8388608
//   meanPart @ 8388608  : 64*8*64*4   = 131072
//   Cout     @ 8519680  : 64*64*4     = 16384   (c = inv_L @ mean, fp32)
//   Mb(bf16) @ 8536064  : 64*4096*2   = 524288  (M = inv_L - I, row-major)

__device__ __forceinline__ short f2bf(float f) {
  union { __hip_bfloat16 h; short s; } u;
  u.h = __float2bfloat16(f);
  return u.s;
}

// ---------------- Kernel 1: partial Gram + row-sum partials ----------------
__global__ __launch_bounds__(256) void k_cov_partial(
    const float* __restrict__ x, float* __restrict__ Spart,
    float* __restrict__ meanPart) {
  const int s = blockIdx.x, b = blockIdx.y;
  const int t = threadIdx.x;
  const int lane = t & 63, w = t >> 6;
  const int wr = w >> 1, wc = w & 1;
  const int hi = lane >> 5;

  __shared__ float T[64 * 64];

  const float* xb = x + (size_t)b * N_DIM * D_DIM + (size_t)s * CHUNK;
  const int jrow = t >> 2, q = t & 3;
  const float* xrow = xb + (size_t)jrow * D_DIM;

  f16vec acc;
#pragma unroll
  for (int r = 0; r < 16; ++r) acc[r] = 0.0f;
  float msum = 0.0f;

  const int r_a = 32 * wr + (lane & 31);
  const int r_b = 32 * wc + (lane & 31);

  f4vec v[4];
#pragma unroll
  for (int i = 0; i < 4; ++i)
    v[i] = *reinterpret_cast<const f4vec*>(xrow + (i * 4 + q) * 4);

  for (int step = 0; step < NSTEP; ++step) {
    __syncthreads();  // previous step's frag reads done; LDS free
#pragma unroll
    for (int i = 0; i < 4; ++i) {
      const int f = i * 4 + q;
      msum += v[i].x + v[i].y + v[i].z + v[i].w;
      *reinterpret_cast<f4vec*>(&T[jrow * 64 + ((f ^ (jrow & 15)) << 2)]) = v[i];
    }
    __syncthreads();  // tile ready
    if (step + 1 < NSTEP) {
      const float* xn = xrow + (step + 1) * 64;
#pragma unroll
      for (int i = 0; i < 4; ++i)
        v[i] = *reinterpret_cast<const f4vec*>(xn + (i * 4 + q) * 4);
    }
#pragma unroll
    for (int ks = 0; ks < 4; ++ks) {
      const int c0 = ks * 4 + hi * 2;
      f4vec a0 = *reinterpret_cast<const f4vec*>(
          &T[r_a * 64 + ((c0 ^ (r_a & 15)) << 2)]);
      f4vec a1 = *reinterpret_cast<const f4vec*>(
          &T[r_a * 64 + (((c0 + 1) ^ (r_a & 15)) << 2)]);
      f4vec b0 = *reinterpret_cast<const f4vec*>(
          &T[r_b * 64 + ((c0 ^ (r_b & 15)) << 2)]);
      f4vec b1 = *reinterpret_cast<const f4vec*>(
          &T[r_b * 64 + (((c0 + 1) ^ (r_b & 15)) << 2)]);
      s8vec af, bf;
      af[0]=f2bf(a0.x); af[1]=f2bf(a0.y); af[2]=f2bf(a0.z); af[3]=f2bf(a0.w);
      af[4]=f2bf(a1.x); af[5]=f2bf(a1.y); af[6]=f2bf(a1.z); af[7]=f2bf(a1.w);
      bf[0]=f2bf(b0.x); bf[1]=f2bf(b0.y); bf[2]=f2bf(b0.z); bf[3]=f2bf(b0.w);
      bf[4]=f2bf(b1.x); bf[5]=f2bf(b1.y); bf[6]=f2bf(b1.z); bf[7]=f2bf(b1.w);
      acc = __builtin_amdgcn_mfma_f32_32x32x16_bf16(af, bf, acc, 0, 0, 0);
    }
  }

  msum += __shfl_xor(msum, 1);
  msum += __shfl_xor(msum, 2);
  if (q == 0) meanPart[(b * SPLIT + s) * 64 + jrow] = msum;

  float* Sp = Spart + (size_t)(b * SPLIT + s) * 4096;
#pragma unroll
  for (int r = 0; r < 16; ++r) {
    const int i = 32 * wr + (r & 3) + 8 * (r >> 2) + 4 * hi;
    const int j = 32 * wc + (lane & 31);
    Sp[i * 64 + j] = acc[r];
  }
}

// ------- Kernel 2: in-register Cholesky + triangular inverse (per wave) ----
// One wave per batch; lane i holds row i of the (symmetric) matrix in 64
// VGPRs. All cross-row communication is v_readlane (no LDS, no barriers).
// Cholesky in unscaled-pivot form: after step k, a[] rows i<=k are frozen
// pivot rows of A-bar where A-bar[i][j] = L[i][j]*sqrt(d_j), diag = d_i.
// Then inv(L) = diag(sqrt(d)) * inv(A-bar): forward-sub on A-bar (lane c =
// column c), X[i][c] = y_i * sqrt(d_i). Zeros above the diagonal fall out
// exactly (0-sums stay 0), so no predication is needed in forward-sub.
__global__ __launch_bounds__(256) void k_chol_inv(
    const float* __restrict__ Spart, const float* __restrict__ meanPart,
    unsigned short* __restrict__ Mb, float* __restrict__ Cout) {
  const int wid = threadIdx.x >> 6, lane = threadIdx.x & 63;
  const int b = blockIdx.x * 4 + wid;

  float a[64];

  // Reduce 8 Gram partials for row `lane` (L2-resident, L1 catches the
  // 16B-of-64B line reuse across neighbor j4).
  {
    const float* base = Spart + (size_t)(b * SPLIT) * 4096 + lane * 64;
#pragma unroll
    for (int j4 = 0; j4 < 16; ++j4) {
      f4vec s = *reinterpret_cast<const f4vec*>(base + j4 * 4);
#pragma unroll
      for (int p = 1; p < SPLIT; ++p)
        s += *reinterpret_cast<const f4vec*>(base + (size_t)p * 4096 + j4 * 4);
      a[j4 * 4 + 0] = s.x; a[j4 * 4 + 1] = s.y;
      a[j4 * 4 + 2] = s.z; a[j4 * 4 + 3] = s.w;
    }
  }

  float mown = 0.0f;
#pragma unroll
  for (int p = 0; p < SPLIT; ++p)
    mown += meanPart[(b * SPLIT + p) * 64 + lane];
  mown *= (1.0f / D_DIM);

  // cov[i][j] = (S[i][j] - D*m_i*m_j) / (D-1)
  {
    const float invD1 = 1.0f / (float)(D_DIM - 1);
    const float miD = mown * (float)D_DIM;
#pragma unroll
    for (int j = 0; j < 64; ++j) {
      float mj = __shfl(mown, j);
      a[j] = (a[j] - miD * mj) * invD1;
    }
  }

  // In-register right-looking Cholesky, unscaled pivots.
#pragma unroll
  for (int k = 0; k < 64; ++k) {
    float dk = __shfl(a[k], k);
    float f = (lane > k) ? a[k] / dk : 0.0f;
#pragma unroll
    for (int j = k + 1; j < 64; ++j) {
      float bc = __shfl(a[j], k);
      a[j] -= f * bc;
    }
  }

  // Forward substitution on A-bar; lane c owns column c of Y.
  float y[64];
#pragma unroll
  for (int i = 0; i < 64; ++i) {
    float s0 = 0.0f, s1 = 0.0f, s2 = 0.0f, s3 = 0.0f;
#pragma unroll
    for (int j = 0; j < i; ++j) {
      float bc = __shfl(a[j], i);  // A-bar[i][j], uniform (SGPR)
      if ((j & 3) == 0) s0 += bc * y[j];
      else if ((j & 3) == 1) s1 += bc * y[j];
      else if ((j & 3) == 2) s2 += bc * y[j];
      else s3 += bc * y[j];
    }
    float d = __shfl(a[i], i);
    float del = (lane == i) ? 1.0f : 0.0f;
    float yi = (del - ((s0 + s1) + (s2 + s3))) / d;
    y[i] = yi;
    float xv = yi * sqrtf(d);  // X[i][lane] = inv_L[i][lane]

    // M = inv_L - I, row i: coalesced 128B u16 store.
    Mb[(size_t)b * 4096 + i * 64 + lane] =
        (unsigned short)f2bf(xv - del);

    // Cvec[i] = sum_c X[i][c] * mean_c
    float cc = xv * mown;
    cc += __shfl_xor(cc, 1);
    cc += __shfl_xor(cc, 2);
    cc += __shfl_xor(cc, 4);
    cc += __shfl_xor(cc, 8);
    cc += __shfl_xor(cc, 16);
    cc += __shfl_xor(cc, 32);
    if (lane == 0) Cout[b * 64 + i] = cc;
  }
}

// ---------------- Kernel 3: out = x + M@x - c*1^T  (LDS-free) --------------
__global__ __launch_bounds__(256) void k_whiten(
    const float* __restrict__ x, const float* __restrict__ Cvec,
    const unsigned short* __restrict__ Mb, float* __restrict__ out) {
  const int b = blockIdx.y;
  const int t = threadIdx.x;
  const int wid = t >> 6, lane = t & 63;
  const int lo = lane & 31, hi = lane >> 5;

  s8vec mfrag[2][4];
  const unsigned short* Mbb = Mb + (size_t)b * 4096;
#pragma unroll
  for (int wr = 0; wr < 2; ++wr)
#pragma unroll
    for (int ks = 0; ks < 4; ++ks)
      mfrag[wr][ks] = *reinterpret_cast<const s8vec*>(
          Mbb + (32 * wr + lo) * 64 + ks * 16 + hi * 8);

  float cv[2][16];
  const float* cb = Cvec + b * 64;
#pragma unroll
  for (int wr = 0; wr < 2; ++wr)
#pragma unroll
    for (int r = 0; r < 16; ++r)
      cv[wr][r] = cb[32 * wr + (r & 3) + 8 * (r >> 2) + 4 * hi];

  const float* xb = x + (size_t)b * N_DIM * D_DIM;
  float* ob = out + (size_t)b * N_DIM * D_DIM;

#pragma unroll
  for (int n = 0; n < 2; ++n) {
    const int d0 = blockIdx.x * 256 + wid * 64 + n * 32;
    f16vec acc0, acc1;
#pragma unroll
    for (int r = 0; r < 16; ++r) { acc0[r] = 0.0f; acc1[r] = 0.0f; }

#pragma unroll
    for (int ks = 0; ks < 4; ++ks) {
      const float* colp = xb + (size_t)(16 * ks + 8 * hi) * D_DIM + d0 + lo;
      s8vec bf;
#pragma unroll
      for (int e = 0; e < 8; ++e) bf[e] = f2bf(colp[(size_t)e * D_DIM]);
      acc0 = __builtin_amdgcn_mfma_f32_32x32x16_bf16(mfrag[0][ks], bf, acc0, 0, 0, 0);
      acc1 = __builtin_amdgcn_mfma_f32_32x32x16_bf16(mfrag[1][ks], bf, acc1, 0, 0, 0);
    }

#pragma unroll
    for (int r = 0; r < 16; ++r) {
      const int row = (r & 3) + 8 * (r >> 2) + 4 * hi;
      const size_t off0 = (size_t)row * D_DIM + d0 + lo;
      ob[off0] = acc0[r] + xb[off0] - cv[0][r];
      const size_t off1 = (size_t)(row + 32) * D_DIM + d0 + lo;
      ob[off1] = acc1[r] + xb[off1] - cv[1][r];
    }
  }
}

extern "C" void kernel_launch(void* const* d_in, const int* in_sizes, int n_in,
                              void* d_out, int out_size, void* d_ws,
                              size_t ws_size, hipStream_t stream) {
  const float* x = (const float*)d_in[0];
  float* out = (float*)d_out;
  char* ws = (char*)d_ws;

  float* Spart = (float*)ws;                            // 8 MB
  float* meanPart = (float*)(ws + 8388608);             // 128 KB
  float* Cout = (float*)(ws + 8519680);                 // 16 KB
  unsigned short* Mb = (unsigned short*)(ws + 8536064); // 512 KB

  k_cov_partial<<<dim3(SPLIT, B_DIM), 256, 0, stream>>>(x, Spart, meanPart);
  k_chol_inv<<<dim3(B_DIM / 4), 256, 0, stream>>>(Spart, meanPart, Mb, Cout);
  k_whiten<<<dim3(D_DIM / 256, B_DIM), 256, 0, stream>>>(x, Cout, Mb, out);
}

// Round 4
// 307.329 us; speedup vs baseline: 1.0860x; 1.0860x over previous
//
#include <hip/hip_runtime.h>
#include <hip/hip_bf16.h>

typedef float f4vec  __attribute__((ext_vector_type(4)));
typedef float f16vec __attribute__((ext_vector_type(16)));
typedef short s8vec  __attribute__((ext_vector_type(8)));

#define B_DIM 64
#define N_DIM 64
#define D_DIM 9216
#define SPLIT 8
#define CHUNK 1152          // D_DIM / SPLIT
#define NSTEP (CHUNK / 64)  // 18

// ws layout (bytes):
//   Spart    @ 0        : 64*8*4096*4 = 8388608
//   meanPart @ 8388608  : 64*8*64*4   = 131072
//   Cout     @ 8519680  : 64*64*4     = 16384   (c = inv_L @ mean, fp32)
//   Mb(bf16) @ 8536064  : 64*4096*2   = 524288  (M = inv_L - I, row-major)

__device__ __forceinline__ short f2bf(float f) {
  union { __hip_bfloat16 h; short s; } u;
  u.h = __float2bfloat16(f);
  return u.s;
}

// Uniform-lane broadcast as explicit v_readlane (SGPR result). Lane index is
// always a compile-time constant here (fully unrolled loops).
__device__ __forceinline__ float rdlane(float v, int l) {
  union { float f; int i; } u;
  u.f = v;
  u.i = __builtin_amdgcn_readlane(u.i, l);
  return u.f;
}

// ---------------- Kernel 1: partial Gram + row-sum partials ----------------
__global__ __launch_bounds__(256) void k_cov_partial(
    const float* __restrict__ x, float* __restrict__ Spart,
    float* __restrict__ meanPart) {
  const int s = blockIdx.x, b = blockIdx.y;
  const int t = threadIdx.x;
  const int lane = t & 63, w = t >> 6;
  const int wr = w >> 1, wc = w & 1;
  const int hi = lane >> 5;

  __shared__ float T[64 * 64];

  const float* xb = x + (size_t)b * N_DIM * D_DIM + (size_t)s * CHUNK;
  const int jrow = t >> 2, q = t & 3;
  const float* xrow = xb + (size_t)jrow * D_DIM;

  f16vec acc;
#pragma unroll
  for (int r = 0; r < 16; ++r) acc[r] = 0.0f;
  float msum = 0.0f;

  const int r_a = 32 * wr + (lane & 31);
  const int r_b = 32 * wc + (lane & 31);

  f4vec v[4];
#pragma unroll
  for (int i = 0; i < 4; ++i)
    v[i] = *reinterpret_cast<const f4vec*>(xrow + (i * 4 + q) * 4);

  for (int step = 0; step < NSTEP; ++step) {
    __syncthreads();  // previous step's frag reads done; LDS free
#pragma unroll
    for (int i = 0; i < 4; ++i) {
      const int f = i * 4 + q;
      msum += v[i].x + v[i].y + v[i].z + v[i].w;
      *reinterpret_cast<f4vec*>(&T[jrow * 64 + ((f ^ (jrow & 15)) << 2)]) = v[i];
    }
    __syncthreads();  // tile ready
    if (step + 1 < NSTEP) {
      const float* xn = xrow + (step + 1) * 64;
#pragma unroll
      for (int i = 0; i < 4; ++i)
        v[i] = *reinterpret_cast<const f4vec*>(xn + (i * 4 + q) * 4);
    }
#pragma unroll
    for (int ks = 0; ks < 4; ++ks) {
      const int c0 = ks * 4 + hi * 2;
      f4vec a0 = *reinterpret_cast<const f4vec*>(
          &T[r_a * 64 + ((c0 ^ (r_a & 15)) << 2)]);
      f4vec a1 = *reinterpret_cast<const f4vec*>(
          &T[r_a * 64 + (((c0 + 1) ^ (r_a & 15)) << 2)]);
      f4vec b0 = *reinterpret_cast<const f4vec*>(
          &T[r_b * 64 + ((c0 ^ (r_b & 15)) << 2)]);
      f4vec b1 = *reinterpret_cast<const f4vec*>(
          &T[r_b * 64 + (((c0 + 1) ^ (r_b & 15)) << 2)]);
      s8vec af, bf;
      af[0]=f2bf(a0.x); af[1]=f2bf(a0.y); af[2]=f2bf(a0.z); af[3]=f2bf(a0.w);
      af[4]=f2bf(a1.x); af[5]=f2bf(a1.y); af[6]=f2bf(a1.z); af[7]=f2bf(a1.w);
      bf[0]=f2bf(b0.x); bf[1]=f2bf(b0.y); bf[2]=f2bf(b0.z); bf[3]=f2bf(b0.w);
      bf[4]=f2bf(b1.x); bf[5]=f2bf(b1.y); bf[6]=f2bf(b1.z); bf[7]=f2bf(b1.w);
      acc = __builtin_amdgcn_mfma_f32_32x32x16_bf16(af, bf, acc, 0, 0, 0);
    }
  }

  msum += __shfl_xor(msum, 1);
  msum += __shfl_xor(msum, 2);
  if (q == 0) meanPart[(b * SPLIT + s) * 64 + jrow] = msum;

  float* Sp = Spart + (size_t)(b * SPLIT + s) * 4096;
#pragma unroll
  for (int r = 0; r < 16; ++r) {
    const int i = 32 * wr + (r & 3) + 8 * (r >> 2) + 4 * hi;
    const int j = 32 * wc + (lane & 31);
    Sp[i * 64 + j] = acc[r];
  }
}

// ------- Kernel 2: in-register Cholesky + triangular inverse (per wave) ----
// ONE WAVE per block (one batch). ~150 VGPRs of live state (a[64]+y[64]);
// __launch_bounds__(64,1) lets the allocator use up to 512 VGPRs -> no
// scratch spill (round-3's 124-VGPR cap spilled and cost 258 us).
// All cross-row communication is v_readlane with constant lane index.
__global__ __launch_bounds__(64, 1) void k_chol_inv(
    const float* __restrict__ Spart, const float* __restrict__ meanPart,
    unsigned short* __restrict__ Mb, float* __restrict__ Cout) {
  const int lane = threadIdx.x;   // 0..63; lane i holds row i
  const int b = blockIdx.x;

  float a[64];

  // Reduce 8 Gram partials for row `lane` (L2-resident).
  {
    const float* base = Spart + (size_t)(b * SPLIT) * 4096 + lane * 64;
#pragma unroll
    for (int j4 = 0; j4 < 16; ++j4) {
      f4vec s = *reinterpret_cast<const f4vec*>(base + j4 * 4);
#pragma unroll
      for (int p = 1; p < SPLIT; ++p)
        s += *reinterpret_cast<const f4vec*>(base + (size_t)p * 4096 + j4 * 4);
      a[j4 * 4 + 0] = s.x; a[j4 * 4 + 1] = s.y;
      a[j4 * 4 + 2] = s.z; a[j4 * 4 + 3] = s.w;
    }
  }

  float mown = 0.0f;
#pragma unroll
  for (int p = 0; p < SPLIT; ++p)
    mown += meanPart[(b * SPLIT + p) * 64 + lane];
  mown *= (1.0f / D_DIM);

  // cov[i][j] = (S[i][j] - D*m_i*m_j) / (D-1)
  {
    const float invD1 = 1.0f / (float)(D_DIM - 1);
    const float miD = mown * (float)D_DIM;
#pragma unroll
    for (int j = 0; j < 64; ++j)
      a[j] = (a[j] - miD * rdlane(mown, j)) * invD1;
  }

  // In-register right-looking Cholesky, unscaled pivots: after step k, row
  // i<=k of a[] is a frozen pivot row of A-bar (A-bar[i][j] = L[i][j]*
  // sqrt(d_j), diag = d_i). Lanes <= k have f=0 -> rows frozen automatically.
#pragma unroll
  for (int k = 0; k < 64; ++k) {
    const float dk = rdlane(a[k], k);
    const float inv = 1.0f / dk;            // uniform (SGPR-sourced)
    const float f = (lane > k) ? a[k] * inv : 0.0f;
#pragma unroll
    for (int j = k + 1; j < 64; ++j)
      a[j] -= f * rdlane(a[j], k);
  }

  // Forward substitution on A-bar; lane c owns column c of Y = inv(A-bar).
  // inv_L = diag(sqrt(d)) * Y. Upper-triangle entries come out exactly 0.
  float y[64];
#pragma unroll
  for (int i = 0; i < 64; ++i) {
    float s0 = 0.0f, s1 = 0.0f, s2 = 0.0f, s3 = 0.0f;
#pragma unroll
    for (int j = 0; j < i; ++j) {
      const float bc = rdlane(a[j], i);  // A-bar[i][j], uniform
      if ((j & 3) == 0) s0 += bc * y[j];
      else if ((j & 3) == 1) s1 += bc * y[j];
      else if ((j & 3) == 2) s2 += bc * y[j];
      else s3 += bc * y[j];
    }
    const float d = rdlane(a[i], i);
    const float invd = 1.0f / d;
    const float del = (lane == i) ? 1.0f : 0.0f;
    const float yi = (del - ((s0 + s1) + (s2 + s3))) * invd;
    y[i] = yi;
    const float xv = yi * sqrtf(d);  // X[i][lane] = inv_L[i][lane]

    // M = inv_L - I, row i: coalesced u16 store.
    Mb[(size_t)b * 4096 + i * 64 + lane] = (unsigned short)f2bf(xv - del);

    // Cvec[i] = sum_c X[i][c] * mean_c
    float cc = xv * mown;
    cc += __shfl_xor(cc, 1);
    cc += __shfl_xor(cc, 2);
    cc += __shfl_xor(cc, 4);
    cc += __shfl_xor(cc, 8);
    cc += __shfl_xor(cc, 16);
    cc += __shfl_xor(cc, 32);
    if (lane == 0) Cout[b * 64 + i] = cc;
  }
}

// ---------------- Kernel 3: out = x + M@x - c*1^T  (LDS-free) --------------
__global__ __launch_bounds__(256) void k_whiten(
    const float* __restrict__ x, const float* __restrict__ Cvec,
    const unsigned short* __restrict__ Mb, float* __restrict__ out) {
  const int b = blockIdx.y;
  const int t = threadIdx.x;
  const int wid = t >> 6, lane = t & 63;
  const int lo = lane & 31, hi = lane >> 5;

  s8vec mfrag[2][4];
  const unsigned short* Mbb = Mb + (size_t)b * 4096;
#pragma unroll
  for (int wr = 0; wr < 2; ++wr)
#pragma unroll
    for (int ks = 0; ks < 4; ++ks)
      mfrag[wr][ks] = *reinterpret_cast<const s8vec*>(
          Mbb + (32 * wr + lo) * 64 + ks * 16 + hi * 8);

  float cv[2][16];
  const float* cb = Cvec + b * 64;
#pragma unroll
  for (int wr = 0; wr < 2; ++wr)
#pragma unroll
    for (int r = 0; r < 16; ++r)
      cv[wr][r] = cb[32 * wr + (r & 3) + 8 * (r >> 2) + 4 * hi];

  const float* xb = x + (size_t)b * N_DIM * D_DIM;
  float* ob = out + (size_t)b * N_DIM * D_DIM;

#pragma unroll
  for (int n = 0; n < 2; ++n) {
    const int d0 = blockIdx.x * 256 + wid * 64 + n * 32;
    f16vec acc0, acc1;
#pragma unroll
    for (int r = 0; r < 16; ++r) { acc0[r] = 0.0f; acc1[r] = 0.0f; }

#pragma unroll
    for (int ks = 0; ks < 4; ++ks) {
      const float* colp = xb + (size_t)(16 * ks + 8 * hi) * D_DIM + d0 + lo;
      s8vec bf;
#pragma unroll
      for (int e = 0; e < 8; ++e) bf[e] = f2bf(colp[(size_t)e * D_DIM]);
      acc0 = __builtin_amdgcn_mfma_f32_32x32x16_bf16(mfrag[0][ks], bf, acc0, 0, 0, 0);
      acc1 = __builtin_amdgcn_mfma_f32_32x32x16_bf16(mfrag[1][ks], bf, acc1, 0, 0, 0);
    }

#pragma unroll
    for (int r = 0; r < 16; ++r) {
      const int row = (r & 3) + 8 * (r >> 2) + 4 * hi;
      const size_t off0 = (size_t)row * D_DIM + d0 + lo;
      ob[off0] = acc0[r] + xb[off0] - cv[0][r];
      const size_t off1 = (size_t)(row + 32) * D_DIM + d0 + lo;
      ob[off1] = acc1[r] + xb[off1] - cv[1][r];
    }
  }
}

extern "C" void kernel_launch(void* const* d_in, const int* in_sizes, int n_in,
                              void* d_out, int out_size, void* d_ws,
                              size_t ws_size, hipStream_t stream) {
  const float* x = (const float*)d_in[0];
  float* out = (float*)d_out;
  char* ws = (char*)d_ws;

  float* Spart = (float*)ws;                            // 8 MB
  float* meanPart = (float*)(ws + 8388608);             // 128 KB
  float* Cout = (float*)(ws + 8519680);                 // 16 KB
  unsigned short* Mb = (unsigned short*)(ws + 8536064); // 512 KB

  k_cov_partial<<<dim3(SPLIT, B_DIM), 256, 0, stream>>>(x, Spart, meanPart);
  k_chol_inv<<<dim3(B_DIM), 64, 0, stream>>>(Spart, meanPart, Mb, Cout);
  k_whiten<<<dim3(D_DIM / 256, B_DIM), 256, 0, stream>>>(x, Cout, Mb, out);
}

// Round 5
// 183.761 us; speedup vs baseline: 1.8163x; 1.6724x over previous
//
#include <hip/hip_runtime.h>
#include <hip/hip_bf16.h>

typedef float f4vec  __attribute__((ext_vector_type(4)));
typedef float f16vec __attribute__((ext_vector_type(16)));
typedef short s8vec  __attribute__((ext_vector_type(8)));

#define B_DIM 64
#define N_DIM 64
#define D_DIM 9216
#define SPLIT 8
#define CHUNK 1152          // D_DIM / SPLIT
#define NSTEP (CHUNK / 64)  // 18

// ws layout (bytes):
//   Spart    @ 0        : 64*8*4096*4 = 8388608
//   meanPart @ 8388608  : 64*8*64*4   = 131072
//   Cout     @ 8519680  : 64*64*4     = 16384   (c = inv_L @ mean, fp32)
//   Mb(bf16) @ 8536064  : 64*4096*2   = 524288  (M = inv_L - I, row-major)

__device__ __forceinline__ short f2bf(float f) {
  union { __hip_bfloat16 h; short s; } u;
  u.h = __float2bfloat16(f);
  return u.s;
}

// v_readlane: static VGPR index, runtime-uniform (SGPR) lane index is legal.
__device__ __forceinline__ float rdlane(float v, int l) {
  union { float f; int i; } u;
  u.f = v;
  u.i = __builtin_amdgcn_readlane(u.i, l);
  return u.f;
}

// ---------------- Kernel 1: partial Gram + row-sum partials ----------------
__global__ __launch_bounds__(256) void k_cov_partial(
    const float* __restrict__ x, float* __restrict__ Spart,
    float* __restrict__ meanPart) {
  const int s = blockIdx.x, b = blockIdx.y;
  const int t = threadIdx.x;
  const int lane = t & 63, w = t >> 6;
  const int wr = w >> 1, wc = w & 1;
  const int hi = lane >> 5;

  __shared__ float T[64 * 64];

  const float* xb = x + (size_t)b * N_DIM * D_DIM + (size_t)s * CHUNK;
  const int jrow = t >> 2, q = t & 3;
  const float* xrow = xb + (size_t)jrow * D_DIM;

  f16vec acc;
#pragma unroll
  for (int r = 0; r < 16; ++r) acc[r] = 0.0f;
  float msum = 0.0f;

  const int r_a = 32 * wr + (lane & 31);
  const int r_b = 32 * wc + (lane & 31);

  f4vec v[4];
#pragma unroll
  for (int i = 0; i < 4; ++i)
    v[i] = *reinterpret_cast<const f4vec*>(xrow + (i * 4 + q) * 4);

  for (int step = 0; step < NSTEP; ++step) {
    __syncthreads();  // previous step's frag reads done; LDS free
#pragma unroll
    for (int i = 0; i < 4; ++i) {
      const int f = i * 4 + q;
      msum += v[i].x + v[i].y + v[i].z + v[i].w;
      *reinterpret_cast<f4vec*>(&T[jrow * 64 + ((f ^ (jrow & 15)) << 2)]) = v[i];
    }
    __syncthreads();  // tile ready
    if (step + 1 < NSTEP) {
      const float* xn = xrow + (step + 1) * 64;
#pragma unroll
      for (int i = 0; i < 4; ++i)
        v[i] = *reinterpret_cast<const f4vec*>(xn + (i * 4 + q) * 4);
    }
#pragma unroll
    for (int ks = 0; ks < 4; ++ks) {
      const int c0 = ks * 4 + hi * 2;
      f4vec a0 = *reinterpret_cast<const f4vec*>(
          &T[r_a * 64 + ((c0 ^ (r_a & 15)) << 2)]);
      f4vec a1 = *reinterpret_cast<const f4vec*>(
          &T[r_a * 64 + (((c0 + 1) ^ (r_a & 15)) << 2)]);
      f4vec b0 = *reinterpret_cast<const f4vec*>(
          &T[r_b * 64 + ((c0 ^ (r_b & 15)) << 2)]);
      f4vec b1 = *reinterpret_cast<const f4vec*>(
          &T[r_b * 64 + (((c0 + 1) ^ (r_b & 15)) << 2)]);
      s8vec af, bf;
      af[0]=f2bf(a0.x); af[1]=f2bf(a0.y); af[2]=f2bf(a0.z); af[3]=f2bf(a0.w);
      af[4]=f2bf(a1.x); af[5]=f2bf(a1.y); af[6]=f2bf(a1.z); af[7]=f2bf(a1.w);
      bf[0]=f2bf(b0.x); bf[1]=f2bf(b0.y); bf[2]=f2bf(b0.z); bf[3]=f2bf(b0.w);
      bf[4]=f2bf(b1.x); bf[5]=f2bf(b1.y); bf[6]=f2bf(b1.z); bf[7]=f2bf(b1.w);
      acc = __builtin_amdgcn_mfma_f32_32x32x16_bf16(af, bf, acc, 0, 0, 0);
    }
  }

  msum += __shfl_xor(msum, 1);
  msum += __shfl_xor(msum, 2);
  if (q == 0) meanPart[(b * SPLIT + s) * 64 + jrow] = msum;

  float* Sp = Spart + (size_t)(b * SPLIT + s) * 4096;
#pragma unroll
  for (int r = 0; r < 16; ++r) {
    const int i = 32 * wr + (r & 3) + 8 * (r >> 2) + 4 * hi;
    const int j = 32 * wc + (lane & 31);
    Sp[i * 64 + j] = acc[r];
  }
}

// ------- Kernel 2: in-register Cholesky + triangular inverse (per wave) ----
// One wave per block (one batch); lane i holds row i in 64 VGPRs.
// Rounds 3/4 fully unrolled this (~8K straight-line instrs) and were
// instruction-fetch latency-bound (VALUBusy 0.5%, ~50 cyc/op). Round 5:
// RUNTIME outer loops (body ~2 KB, I$-resident), all VGPR indices static;
// runtime-uniform values only appear as readlane lane-selects, uniform
// branches, and cndmask capture chains (8-wide, in one block per step).
__global__ __launch_bounds__(64, 1) void k_chol_inv(
    const float* __restrict__ Spart, const float* __restrict__ meanPart,
    unsigned short* __restrict__ Mb, float* __restrict__ Cout) {
  const int lane = threadIdx.x;   // 0..63; lane i holds row i
  const int b = blockIdx.x;

  float a[64];

  // Reduce 8 Gram partials for row `lane` (L2/L3-resident).
  {
    const float* base = Spart + (size_t)(b * SPLIT) * 4096 + lane * 64;
#pragma unroll
    for (int j4 = 0; j4 < 16; ++j4) {
      f4vec s = *reinterpret_cast<const f4vec*>(base + j4 * 4);
#pragma unroll
      for (int p = 1; p < SPLIT; ++p)
        s += *reinterpret_cast<const f4vec*>(base + (size_t)p * 4096 + j4 * 4);
      a[j4 * 4 + 0] = s.x; a[j4 * 4 + 1] = s.y;
      a[j4 * 4 + 2] = s.z; a[j4 * 4 + 3] = s.w;
    }
  }

  float mown = 0.0f;
#pragma unroll
  for (int p = 0; p < SPLIT; ++p)
    mown += meanPart[(b * SPLIT + p) * 64 + lane];
  mown *= (1.0f / D_DIM);

  // cov[i][j] = (S[i][j] - D*m_i*m_j) / (D-1)
  {
    const float invD1 = 1.0f / (float)(D_DIM - 1);
    const float miD = mown * (float)D_DIM;
#pragma unroll
    for (int j = 0; j < 64; ++j)
      a[j] = (a[j] - miD * rdlane(mown, j)) * invD1;
  }

  // In-register right-looking Cholesky, unscaled pivots. m = column k of the
  // working matrix (per-lane multiplier source), recaptured each step via an
  // 8-wide cndmask chain in the single block containing k+1.
  float m = a[0];
#pragma clang loop unroll(disable)
  for (int k = 0; k < 64; ++k) {
    const float d = rdlane(m, k);          // pivot d_k (SGPR)
    const float inv = 1.0f / d;
    const float f = (lane > k) ? m * inv : 0.0f;
#pragma unroll
    for (int jb = 0; jb < 8; ++jb) {
      if (jb * 8 + 8 > k) {                // block has some j > k (uniform)
        const bool mixed = (jb * 8 <= k);
#pragma unroll
        for (int jj = 0; jj < 8; ++jj) {
          const int j = jb * 8 + jj;
          const float bc = rdlane(a[j], k);
          float upd = f * bc;
          if (mixed) upd = (j > k) ? upd : 0.0f;  // keep frozen L-part intact
          a[j] -= upd;
        }
      }
    }
    // Capture next pivot column m = a[k+1] (post-update), 8 cndmask in the
    // one block containing k+1. k=63: (64>>3)=8 matches no block -> no-op.
#pragma unroll
    for (int jb = 0; jb < 8; ++jb) {
      if (((k + 1) >> 3) == jb) {
#pragma unroll
        for (int jj = 0; jj < 8; ++jj) {
          const int j = jb * 8 + jj;
          m = (j == k + 1) ? a[j] : m;
        }
      }
    }
  }

  // One pass: capture own diagonal, zero upper triangle, init y.
  // After zeroing, row i's entries j>i read as exact 0 -> forward-sub
  // accumulation needs no guards (0-products are exact no-ops).
  float diag = 0.0f;
  float y[64];
#pragma unroll
  for (int j = 0; j < 64; ++j) {
    diag = (j == lane) ? a[j] : diag;
    a[j] = (j > lane) ? 0.0f : a[j];
    y[j] = 0.0f;
  }

  // Forward substitution on A-bar; lane c owns column c of Y = inv(A-bar).
  // inv_L = diag(sqrt(d)) * Y.
  const size_t mb_base = (size_t)b * 4096;
#pragma clang loop unroll(disable)
  for (int i = 0; i < 64; ++i) {
    const float d = rdlane(diag, i);
    float s0 = 0.0f, s1 = 0.0f, s2 = 0.0f, s3 = 0.0f;
#pragma unroll
    for (int jb = 0; jb < 8; ++jb) {
      if (jb * 8 <= i) {                   // blocks fully above i are all-0
#pragma unroll
        for (int jj = 0; jj < 8; ++jj) {
          const int j = jb * 8 + jj;
          const float bc = rdlane(a[j], i);  // A-bar[i][j], uniform
          const float pr = bc * y[j];
          if ((jj & 3) == 0) s0 += pr;
          else if ((jj & 3) == 1) s1 += pr;
          else if ((jj & 3) == 2) s2 += pr;
          else s3 += pr;
        }
      }
    }
    const float invd = 1.0f / d;
    const float del = (lane == i) ? 1.0f : 0.0f;
    const float yi = (del - ((s0 + s1) + (s2 + s3))) * invd;
    // y[i] = yi via 8-wide capture chain in the block containing i.
#pragma unroll
    for (int jb = 0; jb < 8; ++jb) {
      if ((i >> 3) == jb) {
#pragma unroll
        for (int jj = 0; jj < 8; ++jj) {
          const int j = jb * 8 + jj;
          y[j] = (j == i) ? yi : y[j];
        }
      }
    }
    const float xv = yi * sqrtf(d);  // X[i][lane] = inv_L[i][lane]

    // M = inv_L - I, row i: coalesced u16 store.
    Mb[mb_base + i * 64 + lane] = (unsigned short)f2bf(xv - del);

    // Cvec[i] = sum_c X[i][c] * mean_c
    float cc = xv * mown;
    cc += __shfl_xor(cc, 1);
    cc += __shfl_xor(cc, 2);
    cc += __shfl_xor(cc, 4);
    cc += __shfl_xor(cc, 8);
    cc += __shfl_xor(cc, 16);
    cc += __shfl_xor(cc, 32);
    if (lane == 0) Cout[b * 64 + i] = cc;
  }
}

// ---------------- Kernel 3: out = x + M@x - c*1^T  (LDS-free) --------------
__global__ __launch_bounds__(256) void k_whiten(
    const float* __restrict__ x, const float* __restrict__ Cvec,
    const unsigned short* __restrict__ Mb, float* __restrict__ out) {
  const int b = blockIdx.y;
  const int t = threadIdx.x;
  const int wid = t >> 6, lane = t & 63;
  const int lo = lane & 31, hi = lane >> 5;

  s8vec mfrag[2][4];
  const unsigned short* Mbb = Mb + (size_t)b * 4096;
#pragma unroll
  for (int wr = 0; wr < 2; ++wr)
#pragma unroll
    for (int ks = 0; ks < 4; ++ks)
      mfrag[wr][ks] = *reinterpret_cast<const s8vec*>(
          Mbb + (32 * wr + lo) * 64 + ks * 16 + hi * 8);

  float cv[2][16];
  const float* cb = Cvec + b * 64;
#pragma unroll
  for (int wr = 0; wr < 2; ++wr)
#pragma unroll
    for (int r = 0; r < 16; ++r)
      cv[wr][r] = cb[32 * wr + (r & 3) + 8 * (r >> 2) + 4 * hi];

  const float* xb = x + (size_t)b * N_DIM * D_DIM;
  float* ob = out + (size_t)b * N_DIM * D_DIM;

#pragma unroll
  for (int n = 0; n < 2; ++n) {
    const int d0 = blockIdx.x * 256 + wid * 64 + n * 32;
    f16vec acc0, acc1;
#pragma unroll
    for (int r = 0; r < 16; ++r) { acc0[r] = 0.0f; acc1[r] = 0.0f; }

#pragma unroll
    for (int ks = 0; ks < 4; ++ks) {
      const float* colp = xb + (size_t)(16 * ks + 8 * hi) * D_DIM + d0 + lo;
      s8vec bf;
#pragma unroll
      for (int e = 0; e < 8; ++e) bf[e] = f2bf(colp[(size_t)e * D_DIM]);
      acc0 = __builtin_amdgcn_mfma_f32_32x32x16_bf16(mfrag[0][ks], bf, acc0, 0, 0, 0);
      acc1 = __builtin_amdgcn_mfma_f32_32x32x16_bf16(mfrag[1][ks], bf, acc1, 0, 0, 0);
    }

#pragma unroll
    for (int r = 0; r < 16; ++r) {
      const int row = (r & 3) + 8 * (r >> 2) + 4 * hi;
      const size_t off0 = (size_t)row * D_DIM + d0 + lo;
      ob[off0] = acc0[r] + xb[off0] - cv[0][r];
      const size_t off1 = (size_t)(row + 32) * D_DIM + d0 + lo;
      ob[off1] = acc1[r] + xb[off1] - cv[1][r];
    }
  }
}

extern "C" void kernel_launch(void* const* d_in, const int* in_sizes, int n_in,
                              void* d_out, int out_size, void* d_ws,
                              size_t ws_size, hipStream_t stream) {
  const float* x = (const float*)d_in[0];
  float* out = (float*)d_out;
  char* ws = (char*)d_ws;

  float* Spart = (float*)ws;                            // 8 MB
  float* meanPart = (float*)(ws + 8388608);             // 128 KB
  float* Cout = (float*)(ws + 8519680);                 // 16 KB
  unsigned short* Mb = (unsigned short*)(ws + 8536064); // 512 KB

  k_cov_partial<<<dim3(SPLIT, B_DIM), 256, 0, stream>>>(x, Spart, meanPart);
  k_chol_inv<<<dim3(B_DIM), 64, 0, stream>>>(Spart, meanPart, Mb, Cout);
  k_whiten<<<dim3(D_DIM / 256, B_DIM), 256, 0, stream>>>(x, Cout, Mb, out);
}

// Round 6
// 170.618 us; speedup vs baseline: 1.9562x; 1.0770x over previous
//
#include <hip/hip_runtime.h>
#include <hip/hip_bf16.h>

typedef float f4vec  __attribute__((ext_vector_type(4)));
typedef float f16vec __attribute__((ext_vector_type(16)));
typedef short s8vec  __attribute__((ext_vector_type(8)));

#define B_DIM 64
#define N_DIM 64
#define D_DIM 9216
#define SPLIT 8
#define CHUNK 1152          // D_DIM / SPLIT
#define NSTEP (CHUNK / 64)  // 18

// ws layout (bytes):
//   Spart    @ 0        : 64*8*4096*4 = 8388608
//   meanPart @ 8388608  : 64*8*64*4   = 131072
//   Cout     @ 8519680  : 64*64*4     = 16384   (c = inv_L @ mean, fp32)
//   Mb(bf16) @ 8536064  : 64*4096*2   = 524288  (M = inv_L - I, row-major)

__device__ __forceinline__ short f2bf(float f) {
  union { __hip_bfloat16 h; short s; } u;
  u.h = __float2bfloat16(f);
  return u.s;
}

// v_readlane: static VGPR index, runtime-uniform (SGPR) lane index is legal.
__device__ __forceinline__ float rdlane(float v, int l) {
  union { float f; int i; } u;
  u.f = v;
  u.i = __builtin_amdgcn_readlane(u.i, l);
  return u.f;
}

// ---------------- Kernel 1: partial Gram + row-sum partials ----------------
__global__ __launch_bounds__(256) void k_cov_partial(
    const float* __restrict__ x, float* __restrict__ Spart,
    float* __restrict__ meanPart) {
  const int s = blockIdx.x, b = blockIdx.y;
  const int t = threadIdx.x;
  const int lane = t & 63, w = t >> 6;
  const int wr = w >> 1, wc = w & 1;
  const int hi = lane >> 5;

  __shared__ float T[64 * 64];

  const float* xb = x + (size_t)b * N_DIM * D_DIM + (size_t)s * CHUNK;
  const int jrow = t >> 2, q = t & 3;
  const float* xrow = xb + (size_t)jrow * D_DIM;

  f16vec acc;
#pragma unroll
  for (int r = 0; r < 16; ++r) acc[r] = 0.0f;
  float msum = 0.0f;

  const int r_a = 32 * wr + (lane & 31);
  const int r_b = 32 * wc + (lane & 31);

  f4vec v[4];
#pragma unroll
  for (int i = 0; i < 4; ++i)
    v[i] = *reinterpret_cast<const f4vec*>(xrow + (i * 4 + q) * 4);

  for (int step = 0; step < NSTEP; ++step) {
    __syncthreads();  // previous step's frag reads done; LDS free
#pragma unroll
    for (int i = 0; i < 4; ++i) {
      const int f = i * 4 + q;
      msum += v[i].x + v[i].y + v[i].z + v[i].w;
      *reinterpret_cast<f4vec*>(&T[jrow * 64 + ((f ^ (jrow & 15)) << 2)]) = v[i];
    }
    __syncthreads();  // tile ready
    if (step + 1 < NSTEP) {
      const float* xn = xrow + (step + 1) * 64;
#pragma unroll
      for (int i = 0; i < 4; ++i)
        v[i] = *reinterpret_cast<const f4vec*>(xn + (i * 4 + q) * 4);
    }
#pragma unroll
    for (int ks = 0; ks < 4; ++ks) {
      const int c0 = ks * 4 + hi * 2;
      f4vec a0 = *reinterpret_cast<const f4vec*>(
          &T[r_a * 64 + ((c0 ^ (r_a & 15)) << 2)]);
      f4vec a1 = *reinterpret_cast<const f4vec*>(
          &T[r_a * 64 + (((c0 + 1) ^ (r_a & 15)) << 2)]);
      f4vec b0 = *reinterpret_cast<const f4vec*>(
          &T[r_b * 64 + ((c0 ^ (r_b & 15)) << 2)]);
      f4vec b1 = *reinterpret_cast<const f4vec*>(
          &T[r_b * 64 + (((c0 + 1) ^ (r_b & 15)) << 2)]);
      s8vec af, bf;
      af[0]=f2bf(a0.x); af[1]=f2bf(a0.y); af[2]=f2bf(a0.z); af[3]=f2bf(a0.w);
      af[4]=f2bf(a1.x); af[5]=f2bf(a1.y); af[6]=f2bf(a1.z); af[7]=f2bf(a1.w);
      bf[0]=f2bf(b0.x); bf[1]=f2bf(b0.y); bf[2]=f2bf(b0.z); bf[3]=f2bf(b0.w);
      bf[4]=f2bf(b1.x); bf[5]=f2bf(b1.y); bf[6]=f2bf(b1.z); bf[7]=f2bf(b1.w);
      acc = __builtin_amdgcn_mfma_f32_32x32x16_bf16(af, bf, acc, 0, 0, 0);
    }
  }

  msum += __shfl_xor(msum, 1);
  msum += __shfl_xor(msum, 2);
  if (q == 0) meanPart[(b * SPLIT + s) * 64 + jrow] = msum;

  float* Sp = Spart + (size_t)(b * SPLIT + s) * 4096;
#pragma unroll
  for (int r = 0; r < 16; ++r) {
    const int i = 32 * wr + (r & 3) + 8 * (r >> 2) + 4 * hi;
    const int j = 32 * wc + (lane & 31);
    Sp[i * 64 + j] = acc[r];
  }
}

// ------- Kernel 2: in-register Cholesky + triangular inverse (per wave) ----
// One wave per block (one batch); lane i holds row i in 64 VGPRs.
// Round-6 changes vs round 5:
//  (a) Cholesky broadcast uses the SYMMETRY of the trailing block:
//      A[k][j] = A[j][k] = lane j's pivot-column register m. All 64
//      readlanes per step hit ONE register (written once/step) instead of
//      64 freshly-written registers -> 1 RAW hazard/step instead of 64.
//  (b) Cvec's dependent 6-deep shfl chain moved out of the fwd-sub loop
//      into a post-loop batch of 64 independent butterflies.
//  (c) v_rcp/v_sqrt instead of IEEE div/sqrt sequences (err ~1e-7,
//      negligible vs the bf16-dominated 0.031 absmax).
__global__ __launch_bounds__(64, 1) void k_chol_inv(
    const float* __restrict__ Spart, const float* __restrict__ meanPart,
    unsigned short* __restrict__ Mb, float* __restrict__ Cout) {
  const int lane = threadIdx.x;   // 0..63; lane i holds row i
  const int b = blockIdx.x;

  float a[64];

  // Reduce 8 Gram partials for row `lane` (L2/L3-resident).
  {
    const float* base = Spart + (size_t)(b * SPLIT) * 4096 + lane * 64;
#pragma unroll
    for (int j4 = 0; j4 < 16; ++j4) {
      f4vec s = *reinterpret_cast<const f4vec*>(base + j4 * 4);
#pragma unroll
      for (int p = 1; p < SPLIT; ++p)
        s += *reinterpret_cast<const f4vec*>(base + (size_t)p * 4096 + j4 * 4);
      a[j4 * 4 + 0] = s.x; a[j4 * 4 + 1] = s.y;
      a[j4 * 4 + 2] = s.z; a[j4 * 4 + 3] = s.w;
    }
  }

  float mown = 0.0f;
#pragma unroll
  for (int p = 0; p < SPLIT; ++p)
    mown += meanPart[(b * SPLIT + p) * 64 + lane];
  mown *= (1.0f / D_DIM);

  // cov[i][j] = (S[i][j] - D*m_i*m_j) / (D-1)
  {
    const float invD1 = 1.0f / (float)(D_DIM - 1);
    const float miD = mown * (float)D_DIM;
#pragma unroll
    for (int j = 0; j < 64; ++j)
      a[j] = (a[j] - miD * rdlane(mown, j)) * invD1;
  }

  // In-register right-looking Cholesky, unscaled pivots. m = pivot column k
  // (lane i's m = A[i][k]), maintained by an 8-wide cndmask capture chain.
  // Broadcast row k via symmetry: A[k][j] = A[j][k] = rdlane(m, j).
  float m = a[0];
#pragma clang loop unroll(disable)
  for (int k = 0; k < 64; ++k) {
    const float d = rdlane(m, k);                   // pivot d_k
    const float inv = __builtin_amdgcn_rcpf(d);
    const float f = (lane > k) ? m * inv : 0.0f;
#pragma unroll
    for (int jb = 0; jb < 8; ++jb) {
      if (jb * 8 + 8 > k) {                // block has some j > k (uniform)
        const bool mixed = (jb * 8 <= k);
#pragma unroll
        for (int jj = 0; jj < 8; ++jj) {
          const int j = jb * 8 + jj;
          const float bc = rdlane(m, j);   // A[k][j] by trailing symmetry
          float upd = f * bc;
          if (mixed) upd = (j > k) ? upd : 0.0f;  // keep frozen part intact
          a[j] -= upd;
        }
      }
    }
    // Capture next pivot column m = a[k+1] (post-update). k=63: no-op.
#pragma unroll
    for (int jb = 0; jb < 8; ++jb) {
      if (((k + 1) >> 3) == jb) {
#pragma unroll
        for (int jj = 0; jj < 8; ++jj) {
          const int j = jb * 8 + jj;
          m = (j == k + 1) ? a[j] : m;
        }
      }
    }
  }

  // Capture own diagonal d_lane; init y. (Upper-triangle a-values are only
  // ever multiplied by y[j]=0 in fwd-sub, so no zeroing pass is needed.)
  float diag = 0.0f;
  float y[64];
#pragma unroll
  for (int j = 0; j < 64; ++j) {
    diag = (j == lane) ? a[j] : diag;
    y[j] = 0.0f;
  }
  const float sqd_own = __builtin_amdgcn_sqrtf(diag);

  // Forward substitution on A-bar; lane c owns column c of Y = inv(A-bar).
  // inv_L = diag(sqrt(d)) * Y. a[] is frozen -> readlanes are hazard-free.
  const size_t mb_base = (size_t)b * 4096;
#pragma clang loop unroll(disable)
  for (int i = 0; i < 64; ++i) {
    const float d = rdlane(diag, i);
    float s0 = 0.0f, s1 = 0.0f;
#pragma unroll
    for (int jb = 0; jb < 8; ++jb) {
      if (jb * 8 <= i) {                   // blocks fully above i: y==0
#pragma unroll
        for (int jj = 0; jj < 8; ++jj) {
          const int j = jb * 8 + jj;
          const float bc = rdlane(a[j], i);  // A-bar[i][j], uniform
          const float pr = bc * y[j];
          if (jj & 1) s1 += pr; else s0 += pr;
        }
      }
    }
    const float invd = __builtin_amdgcn_rcpf(d);
    const float del = (lane == i) ? 1.0f : 0.0f;
    const float yi = (del - (s0 + s1)) * invd;
    // y[i] = yi via 8-wide capture chain in the block containing i.
#pragma unroll
    for (int jb = 0; jb < 8; ++jb) {
      if ((i >> 3) == jb) {
#pragma unroll
        for (int jj = 0; jj < 8; ++jj) {
          const int j = jb * 8 + jj;
          y[j] = (j == i) ? yi : y[j];
        }
      }
    }
    const float xv = yi * __builtin_amdgcn_sqrtf(d);  // inv_L[i][lane]
    // M = inv_L - I, row i: coalesced u16 store.
    Mb[mb_base + i * 64 + lane] = (unsigned short)f2bf(xv - del);
  }

  // Cvec[i] = sqrt(d_i) * sum_c Y[i][c]*mean_c. 64 INDEPENDENT butterflies
  // (interleaved by the scheduler), one cndmask capture each; lane i ends
  // holding S_i, scales by its own sqrt(diag), single coalesced store.
  float res = 0.0f;
#pragma unroll
  for (int i = 0; i < 64; ++i) {
    float t2 = y[i] * mown;
    t2 += __shfl_xor(t2, 1);
    t2 += __shfl_xor(t2, 2);
    t2 += __shfl_xor(t2, 4);
    t2 += __shfl_xor(t2, 8);
    t2 += __shfl_xor(t2, 16);
    t2 += __shfl_xor(t2, 32);
    res = (lane == i) ? t2 : res;
  }
  Cout[b * 64 + lane] = res * sqd_own;
}

// ---------------- Kernel 3: out = x + M@x - c*1^T  (LDS-free) --------------
__global__ __launch_bounds__(256) void k_whiten(
    const float* __restrict__ x, const float* __restrict__ Cvec,
    const unsigned short* __restrict__ Mb, float* __restrict__ out) {
  const int b = blockIdx.y;
  const int t = threadIdx.x;
  const int wid = t >> 6, lane = t & 63;
  const int lo = lane & 31, hi = lane >> 5;

  s8vec mfrag[2][4];
  const unsigned short* Mbb = Mb + (size_t)b * 4096;
#pragma unroll
  for (int wr = 0; wr < 2; ++wr)
#pragma unroll
    for (int ks = 0; ks < 4; ++ks)
      mfrag[wr][ks] = *reinterpret_cast<const s8vec*>(
          Mbb + (32 * wr + lo) * 64 + ks * 16 + hi * 8);

  float cv[2][16];
  const float* cb = Cvec + b * 64;
#pragma unroll
  for (int wr = 0; wr < 2; ++wr)
#pragma unroll
    for (int r = 0; r < 16; ++r)
      cv[wr][r] = cb[32 * wr + (r & 3) + 8 * (r >> 2) + 4 * hi];

  const float* xb = x + (size_t)b * N_DIM * D_DIM;
  float* ob = out + (size_t)b * N_DIM * D_DIM;

#pragma unroll
  for (int n = 0; n < 2; ++n) {
    const int d0 = blockIdx.x * 256 + wid * 64 + n * 32;
    f16vec acc0, acc1;
#pragma unroll
    for (int r = 0; r < 16; ++r) { acc0[r] = 0.0f; acc1[r] = 0.0f; }

#pragma unroll
    for (int ks = 0; ks < 4; ++ks) {
      const float* colp = xb + (size_t)(16 * ks + 8 * hi) * D_DIM + d0 + lo;
      s8vec bf;
#pragma unroll
      for (int e = 0; e < 8; ++e) bf[e] = f2bf(colp[(size_t)e * D_DIM]);
      acc0 = __builtin_amdgcn_mfma_f32_32x32x16_bf16(mfrag[0][ks], bf, acc0, 0, 0, 0);
      acc1 = __builtin_amdgcn_mfma_f32_32x32x16_bf16(mfrag[1][ks], bf, acc1, 0, 0, 0);
    }

#pragma unroll
    for (int r = 0; r < 16; ++r) {
      const int row = (r & 3) + 8 * (r >> 2) + 4 * hi;
      const size_t off0 = (size_t)row * D_DIM + d0 + lo;
      ob[off0] = acc0[r] + xb[off0] - cv[0][r];
      const size_t off1 = (size_t)(row + 32) * D_DIM + d0 + lo;
      ob[off1] = acc1[r] + xb[off1] - cv[1][r];
    }
  }
}

extern "C" void kernel_launch(void* const* d_in, const int* in_sizes, int n_in,
                              void* d_out, int out_size, void* d_ws,
                              size_t ws_size, hipStream_t stream) {
  const float* x = (const float*)d_in[0];
  float* out = (float*)d_out;
  char* ws = (char*)d_ws;

  float* Spart = (float*)ws;                            // 8 MB
  float* meanPart = (float*)(ws + 8388608);             // 128 KB
  float* Cout = (float*)(ws + 8519680);                 // 16 KB
  unsigned short* Mb = (unsigned short*)(ws + 8536064); // 512 KB

  k_cov_partial<<<dim3(SPLIT, B_DIM), 256, 0, stream>>>(x, Spart, meanPart);
  k_chol_inv<<<dim3(B_DIM), 64, 0, stream>>>(Spart, meanPart, Mb, Cout);
  k_whiten<<<dim3(D_DIM / 256, B_DIM), 256, 0, stream>>>(x, Cout, Mb, out);
}